// Round 9
// baseline (554.132 us; speedup 1.0000x reference)
//
#include <hip/hip_runtime.h>

// PretrainedCNN: normalized-convolution U-Net, B=16, 512x640, NC=2.
// Inputs fp32; OUTPUT d_out fp32: xout plane (n0) then cout plane (n0).
// Round 9: enc_full rewritten — 4x2 register blocking (6-row window reused
// across 2 output rows), float4-typed LDS (forced b128), bank-phase-padded
// strides (s0: 44->52 = all-2-way-free), in-thread 2x2 pool, 128-thr blocks.

#define NB 16

constexpr int TX = 32, TY = 8;

// ================= fused full-res encoder =================
constexpr int FTW = 32, FTH = 16;
constexpr int FSH = 28;            // input stage rows (halo 6)
constexpr int FSW4 = 13;           // stage row stride in float4 (52 floats; logical 44)
constexpr int FAH = 24;            // L1 out rows (halo 4)
constexpr int FAW4 = 10;           // 40 floats
constexpr int FBH = 20;            // L2 out rows (halo 2)
constexpr int FBW4 = 9;            // 36 floats

// 5x5 conv over an 8-wide x 6-tall window: 4 cols x 2 rows of outputs.
template<int CIN>
__device__ __forceinline__ void conv5_2x4(
    const float4* __restrict__ sc4, const float4* __restrict__ sp4,
    int chStride4, int sw4, int row0, int j,
    const float* __restrict__ w,
    float ca[2][2][4], float pa[2][2][4])
{
#pragma unroll
    for (int o = 0; o < 2; ++o)
#pragma unroll
        for (int r = 0; r < 2; ++r)
#pragma unroll
            for (int jj = 0; jj < 4; ++jj) { ca[o][r][jj] = 0.f; pa[o][r][jj] = 0.f; }
#pragma unroll
    for (int ci = 0; ci < CIN; ++ci) {
        const int base = ci * chStride4 + row0 * sw4 + j;
#pragma unroll
        for (int d = 0; d < 6; ++d) {
            const float4 c0 = sc4[base + d * sw4];
            const float4 c1 = sc4[base + d * sw4 + 1];
            const float4 p0 = sp4[base + d * sw4];
            const float4 p1 = sp4[base + d * sw4 + 1];
            const float cw[8] = {c0.x, c0.y, c0.z, c0.w, c1.x, c1.y, c1.z, c1.w};
            const float pw[8] = {p0.x, p0.y, p0.z, p0.w, p1.x, p1.y, p1.z, p1.w};
#pragma unroll
            for (int r = 0; r < 2; ++r) {
                const int kh = d - r;
                if (kh < 0 || kh > 4) continue;
#pragma unroll
                for (int o = 0; o < 2; ++o)
#pragma unroll
                    for (int kw = 0; kw < 5; ++kw) {
                        const float wv = w[(o * CIN + ci) * 25 + kh * 5 + kw];
#pragma unroll
                        for (int jj = 0; jj < 4; ++jj) {
                            ca[o][r][jj] += wv * cw[jj + kw];
                            pa[o][r][jj] += wv * pw[jj + kw];
                        }
                    }
            }
        }
    }
}

// s0 (input stage) and s2 (L2 output) never live simultaneously: overlay.
union EncSmem {
    struct { float4 c[FSH][FSW4], p[FSH][FSW4]; } s0;          // 11648 B
    struct { float4 c[2][FBH][FBW4], p[2][FBH][FBW4]; } s2;    // 11520 B
};

__global__ __launch_bounds__(128)
void enc_full_kernel(const float* __restrict__ x0, const float* __restrict__ c0,
                     const float* __restrict__ w1, const float* __restrict__ b1,
                     const float* __restrict__ w2, const float* __restrict__ b2,
                     const float* __restrict__ w3, const float* __restrict__ b3,
                     float* __restrict__ FAx, float* __restrict__ FAc,
                     float* __restrict__ HPx, float* __restrict__ HPc,
                     int H, int W) {
    __shared__ EncSmem u;
    __shared__ float4 s1c[2][FAH][FAW4], s1p[2][FAH][FAW4];    // 15360 B

    const int tid = threadIdx.x;
    const int b = blockIdx.z;
    const int Y0 = blockIdx.y * FTH, X0 = blockIdx.x * FTW;
    const int npix = H * W;
    const size_t bofs = (size_t)b * npix;
    const size_t chs = (size_t)NB * npix;

    auto wsum = [](const float* w, int n) { float s = 0.f; for (int i = 0; i < n; ++i) s += w[i]; return s; };
    const float inv1[2] = {1.f / wsum(w1, 25),  1.f / wsum(w1 + 25, 25)};
    const float inv2[2] = {1.f / wsum(w2, 50),  1.f / wsum(w2 + 50, 50)};
    const float inv3[2] = {1.f / wsum(w3, 50),  1.f / wsum(w3 + 50, 50)};
    const float bb1[2] = {b1[0], b1[1]};
    const float bb2[2] = {b2[0], b2[1]};
    const float bb3[2] = {b3[0], b3[1]};

    // ---- stage input tile (zero-padded outside image); logical cols 44, stride 52
    {
        float* s0c = (float*)u.s0.c;
        float* s0p = (float*)u.s0.p;
        for (int i = tid; i < FSH * 44; i += 128) {
            const int ly = i / 44, lx = i - ly * 44;
            const int gy = Y0 + ly - 6, gx = X0 + lx - 6;
            float cv = 0.f, pv = 0.f;
            if (gy >= 0 && gy < H && gx >= 0 && gx < W) {
                const size_t o = bofs + (size_t)gy * W + gx;
                cv = c0[o]; pv = x0[o] * cv;
            }
            s0c[ly * (4 * FSW4) + lx] = cv;
            s0p[ly * (4 * FSW4) + lx] = pv;
        }
    }
    __syncthreads();

    // ---- L1: out 24x40 (CIN=1), 120 threads, rows 2rp..2rp+1, cols 4j..4j+3
    if (tid < 120) {
        const int rp = tid / 10, j = tid % 10;
        float ca[2][2][4], pa[2][2][4];
        conv5_2x4<1>((const float4*)u.s0.c, (const float4*)u.s0.p, 0, FSW4, 2 * rp, j, w1, ca, pa);
#pragma unroll
        for (int r = 0; r < 2; ++r) {
            const int oy = 2 * rp + r;
            const int gy = Y0 + oy - 4;
#pragma unroll
            for (int o = 0; o < 2; ++o) {
                float cq[4], pq[4];
#pragma unroll
                for (int jj = 0; jj < 4; ++jj) {
                    const int gx = X0 + 4 * j + jj - 4;
                    const bool in = (gy >= 0 && gy < H && gx >= 0 && gx < W);
                    const float cv = in ? ca[o][r][jj] * inv1[o] : 0.f;
                    cq[jj] = cv;
                    pq[jj] = in ? (pa[o][r][jj] / (ca[o][r][jj] + 1e-20f) + bb1[o]) * cv : 0.f;
                }
                s1c[o][oy][j] = make_float4(cq[0], cq[1], cq[2], cq[3]);
                s1p[o][oy][j] = make_float4(pq[0], pq[1], pq[2], pq[3]);
            }
        }
    }
    __syncthreads();   // L1 done reading s0 -> s2 may overwrite the union

    // ---- L2: out 20x36 (CIN=2), 90 threads
    if (tid < 90) {
        const int rp = tid / 9, j = tid % 9;
        float ca[2][2][4], pa[2][2][4];
        conv5_2x4<2>((const float4*)s1c, (const float4*)s1p, FAH * FAW4, FAW4, 2 * rp, j, w2, ca, pa);
#pragma unroll
        for (int r = 0; r < 2; ++r) {
            const int oy = 2 * rp + r;
            const int gy = Y0 + oy - 2;
#pragma unroll
            for (int o = 0; o < 2; ++o) {
                float cq[4], pq[4];
#pragma unroll
                for (int jj = 0; jj < 4; ++jj) {
                    const int gx = X0 + 4 * j + jj - 2;
                    const bool in = (gy >= 0 && gy < H && gx >= 0 && gx < W);
                    const float cv = in ? ca[o][r][jj] * inv2[o] : 0.f;
                    cq[jj] = cv;
                    pq[jj] = in ? (pa[o][r][jj] / (ca[o][r][jj] + 1e-20f) + bb2[o]) * cv : 0.f;
                }
                u.s2.c[o][oy][j] = make_float4(cq[0], cq[1], cq[2], cq[3]);
                u.s2.p[o][oy][j] = make_float4(pq[0], pq[1], pq[2], pq[3]);
            }
        }
    }
    __syncthreads();

    // ---- L3: out 16x32 (CIN=2), 64 threads -> global FA + in-thread 2x2 pool -> HP
    if (tid < 64) {
        const int rp = tid / 8, j = tid % 8;
        float ca[2][2][4], pa[2][2][4];
        conv5_2x4<2>((const float4*)u.s2.c, (const float4*)u.s2.p, FBH * FBW4, FBW4, 2 * rp, j, w3, ca, pa);
        float xv[2][2][4], cv[2][2][4];
#pragma unroll
        for (int o = 0; o < 2; ++o)
#pragma unroll
            for (int r = 0; r < 2; ++r)
#pragma unroll
                for (int jj = 0; jj < 4; ++jj) {
                    xv[o][r][jj] = pa[o][r][jj] / (ca[o][r][jj] + 1e-20f) + bb3[o];
                    cv[o][r][jj] = ca[o][r][jj] * inv3[o];
                }
#pragma unroll
        for (int r = 0; r < 2; ++r) {
            const int gy = Y0 + 2 * rp + r;
            const size_t base = bofs + (size_t)gy * W + (X0 + 4 * j);
#pragma unroll
            for (int o = 0; o < 2; ++o) {
                *(float4*)(FAx + o * chs + base) = make_float4(xv[o][r][0], xv[o][r][1], xv[o][r][2], xv[o][r][3]);
                *(float4*)(FAc + o * chs + base) = make_float4(cv[o][r][0], cv[o][r][1], cv[o][r][2], cv[o][r][3]);
            }
        }
        // 2x2 pool, first-wins argmax of c, both rows in-thread
        const int Wh = W >> 1;
        const int np1 = (H >> 1) * Wh;
        const int hy = (Y0 >> 1) + rp;
        const int hx = (X0 >> 1) + 2 * j;
#pragma unroll
        for (int o = 0; o < 2; ++o)
#pragma unroll
            for (int g = 0; g < 2; ++g) {
                const float c00 = cv[o][0][2 * g], c01 = cv[o][0][2 * g + 1];
                const float c10 = cv[o][1][2 * g], c11 = cv[o][1][2 * g + 1];
                const float x00 = xv[o][0][2 * g], x01 = xv[o][0][2 * g + 1];
                const float x10 = xv[o][1][2 * g], x11 = xv[o][1][2 * g + 1];
                float bc = c00, bx = x00;
                if (c01 > bc) { bc = c01; bx = x01; }
                if (c10 > bc) { bc = c10; bx = x10; }
                if (c11 > bc) { bc = c11; bx = x11; }
                const size_t ho = (size_t)o * NB * np1 + (size_t)b * np1 + (size_t)hy * Wh + hx + g;
                HPc[ho] = bc * 0.25f;
                HPx[ho] = bx;
            }
    }
}

// ================= original (validated) kernels for sub-res =================
template<int CIN>
__global__ __launch_bounds__(256)
void navg5_kernel(const float* __restrict__ xin, const float* __restrict__ cin,
                  const float* __restrict__ w, const float* __restrict__ bias,
                  float* __restrict__ xout, float* __restrict__ cout,
                  int H, int W) {
    __shared__ float sc[CIN][TY + 4][TX + 4];
    __shared__ float sp[CIN][TY + 4][TX + 4];
    __shared__ float sw[2 * CIN * 25];
    __shared__ float sb[2];
    __shared__ float sinv[2];

    const int b = blockIdx.z;
    const int npix = H * W;
    const size_t chs = (size_t)NB * npix;
    const int tid = threadIdx.y * TX + threadIdx.x;

    for (int i = tid; i < 2 * CIN * 25; i += 256) sw[i] = w[i];
    __syncthreads();
    if (tid < 2) {
        float s = 0.f;
        for (int i = 0; i < CIN * 25; ++i) s += sw[tid * CIN * 25 + i];
        sinv[tid] = 1.f / s;
        sb[tid] = bias[tid];
    }

    const int y0 = blockIdx.y * TY - 2;
    const int x0 = blockIdx.x * TX - 2;
    for (int ci = 0; ci < CIN; ++ci) {
        const size_t base = (size_t)ci * chs + (size_t)b * npix;
        for (int i = tid; i < (TY + 4) * (TX + 4); i += 256) {
            const int ly = i / (TX + 4), lx = i % (TX + 4);
            const int gy = y0 + ly, gx = x0 + lx;
            float cv = 0.f, pv = 0.f;
            if (gy >= 0 && gy < H && gx >= 0 && gx < W) {
                const size_t o = base + (size_t)gy * W + gx;
                cv = cin[o];
                pv = xin[o] * cv;
            }
            sc[ci][ly][lx] = cv;
            sp[ci][ly][lx] = pv;
        }
    }
    __syncthreads();

    const int gh = blockIdx.y * TY + threadIdx.y;
    const int gw = blockIdx.x * TX + threadIdx.x;
    if (gh < H && gw < W) {
        const size_t off = (size_t)b * npix + (size_t)gh * W + gw;
#pragma unroll
        for (int o = 0; o < 2; ++o) {
            float ca = 0.f, pa = 0.f;
#pragma unroll
            for (int ci = 0; ci < CIN; ++ci)
#pragma unroll
                for (int kh = 0; kh < 5; ++kh)
#pragma unroll
                    for (int kw = 0; kw < 5; ++kw) {
                        const float wv = sw[((o * CIN + ci) * 5 + kh) * 5 + kw];
                        ca += wv * sc[ci][threadIdx.y + kh][threadIdx.x + kw];
                        pa += wv * sp[ci][threadIdx.y + kh][threadIdx.x + kw];
                    }
            xout[(size_t)o * chs + off] = pa / (ca + 1e-20f) + sb[o];
            cout[(size_t)o * chs + off] = ca * sinv[o];
        }
    }
}

__global__ void pool_kernel(const float* __restrict__ xin, const float* __restrict__ cin,
                            float* __restrict__ xout, float* __restrict__ cout,
                            int Hh, int Wh) {
    const int nplane = Hh * Wh;
    const int total = 2 * NB * nplane;
    const int idx = blockIdx.x * blockDim.x + threadIdx.x;
    if (idx >= total) return;
    const int p = idx / nplane;
    const int q = idx - p * nplane;
    const int h = q / Wh, wc = q - h * Wh;
    const int Wf = 2 * Wh;
    const size_t ibase = (size_t)p * 4 * nplane + (size_t)(2 * h) * Wf + 2 * wc;
    const float c00 = cin[ibase], c01 = cin[ibase + 1];
    const float c10 = cin[ibase + Wf], c11 = cin[ibase + Wf + 1];
    float best = c00; size_t boff = ibase;
    if (c01 > best) { best = c01; boff = ibase + 1; }
    if (c10 > best) { best = c10; boff = ibase + Wf; }
    if (c11 > best) { best = c11; boff = ibase + Wf + 1; }
    cout[idx] = best * 0.25f;
    xout[idx] = xin[boff];
}

template<bool UPA, bool UPB, bool FUSE>
__global__ __launch_bounds__(256)
void navg3_kernel(const float* __restrict__ xA, const float* __restrict__ cA,
                  const float* __restrict__ xB, const float* __restrict__ cB,
                  const float* __restrict__ w, const float* __restrict__ bias,
                  const float* __restrict__ w4, const float* __restrict__ b4,
                  float* __restrict__ xout, float* __restrict__ cout,
                  int H, int W) {
    __shared__ float sc[4][TY + 2][TX + 2];
    __shared__ float sp[4][TY + 2][TX + 2];
    __shared__ float sw[72];
    __shared__ float sb[2];
    __shared__ float sinv[2];

    const int b = blockIdx.z;
    const int npix = H * W;
    const size_t chs = (size_t)NB * npix;
    const int tid = threadIdx.y * TX + threadIdx.x;

    if (tid < 72) sw[tid] = w[tid];
    __syncthreads();
    if (tid < 2) {
        float s = 0.f;
        for (int i = 0; i < 36; ++i) s += sw[tid * 36 + i];
        sinv[tid] = 1.f / s;
        sb[tid] = bias[tid];
    }

    const int y0 = blockIdx.y * TY - 1;
    const int x0 = blockIdx.x * TX - 1;
    const int Ws2 = W >> 1;
    const int npixS = (H >> 1) * Ws2;

#pragma unroll
    for (int ch = 0; ch < 4; ++ch) {
        const bool up = (ch < 2) ? UPA : UPB;
        const float* xs = (ch < 2) ? xA : xB;
        const float* cs = (ch < 2) ? cA : cB;
        const int sch = ch & 1;
        const size_t base = up ? ((size_t)sch * NB * npixS + (size_t)b * npixS)
                               : ((size_t)sch * chs + (size_t)b * npix);
        for (int i = tid; i < (TY + 2) * (TX + 2); i += 256) {
            const int ly = i / (TX + 2), lx = i % (TX + 2);
            const int gy = y0 + ly, gx = x0 + lx;
            float cv = 0.f, pv = 0.f;
            if (gy >= 0 && gy < H && gx >= 0 && gx < W) {
                const size_t o = up ? (base + (size_t)(gy >> 1) * Ws2 + (gx >> 1))
                                    : (base + (size_t)gy * W + gx);
                cv = cs[o];
                pv = xs[o] * cv;
            }
            sc[ch][ly][lx] = cv;
            sp[ch][ly][lx] = pv;
        }
    }
    __syncthreads();

    const int gh = blockIdx.y * TY + threadIdx.y;
    const int gw = blockIdx.x * TX + threadIdx.x;
    if (gh < H && gw < W) {
        const size_t off = (size_t)b * npix + (size_t)gh * W + gw;
        float xv[2], cv[2];
#pragma unroll
        for (int o = 0; o < 2; ++o) {
            float ca = 0.f, pa = 0.f;
#pragma unroll
            for (int ci = 0; ci < 4; ++ci)
#pragma unroll
                for (int kh = 0; kh < 3; ++kh)
#pragma unroll
                    for (int kw = 0; kw < 3; ++kw) {
                        const float wv = sw[((o * 4 + ci) * 3 + kh) * 3 + kw];
                        ca += wv * sc[ci][threadIdx.y + kh][threadIdx.x + kw];
                        pa += wv * sp[ci][threadIdx.y + kh][threadIdx.x + kw];
                    }
            xv[o] = pa / (ca + 1e-20f) + sb[o];
            cv[o] = ca * sinv[o];
        }
        if (FUSE) {
            const float w40 = w4[0], w41 = w4[1];
            const float ca4 = w40 * cv[0] + w41 * cv[1];
            const float xo = (w40 * xv[0] * cv[0] + w41 * xv[1] * cv[1]) / (ca4 + 1e-20f) + b4[0];
            const float co = ca4 / (w40 + w41);
            xout[off] = xo;
            cout[off] = co;
        } else {
            xout[off] = xv[0]; xout[chs + off] = xv[1];
            cout[off] = cv[0]; cout[chs + off] = cv[1];
        }
    }
}

extern "C" void kernel_launch(void* const* d_in, const int* in_sizes, int n_in,
                              void* d_out, int out_size, void* d_ws, size_t ws_size,
                              hipStream_t stream) {
    const float* x0  = (const float*)d_in[0];
    const float* c0  = (const float*)d_in[1];
    const float* w1  = (const float*)d_in[2];
    const float* w2  = (const float*)d_in[3];
    const float* w3  = (const float*)d_in[4];
    const float* w4  = (const float*)d_in[5];
    const float* w34 = (const float*)d_in[6];
    const float* w23 = (const float*)d_in[7];
    const float* w12 = (const float*)d_in[8];
    const float* b1  = (const float*)d_in[9];
    const float* b2  = (const float*)d_in[10];
    const float* b3  = (const float*)d_in[11];
    const float* b4  = (const float*)d_in[12];
    const float* b34 = (const float*)d_in[13];
    const float* b23 = (const float*)d_in[14];
    const float* b12 = (const float*)d_in[15];

    float* out = (float*)d_out;   // fp32: xout plane then cout plane

    const int H0 = 512, W0 = 640, H1 = 256, W1 = 320, H2 = 128, W2 = 160, H3 = 64, W3 = 80;
    const size_t n0 = (size_t)NB * H0 * W0;
    const size_t n1 = n0 / 4, n2 = n0 / 16, n3 = n0 / 64;

    float* ws = (float*)d_ws;
    float* FAx = ws;            // x1 (2ch) -- persists to the end
    float* FAc = ws + 2 * n0;   // c1 (2ch)
    float* sub = ws + 4 * n0;   // sub-res arena
    float* HPx = sub;               sub += 2 * n1;
    float* HPc = sub;               sub += 2 * n1;
    float* HAx = sub;               sub += 2 * n1;
    float* HAc = sub;               sub += 2 * n1;
    float* QPx = sub;               sub += 2 * n2;
    float* QPc = sub;               sub += 2 * n2;
    float* QAx = sub;               sub += 2 * n2;
    float* QAc = sub;               sub += 2 * n2;
    float* EPx = sub;               sub += 2 * n3;
    float* EPc = sub;               sub += 2 * n3;
    float* EAx = sub;               sub += 2 * n3;
    float* EAc = sub;               sub += 2 * n3;

    dim3 blk(TX, TY);
    auto gdim = [](int W, int H) { return dim3((W + TX - 1) / TX, (H + TY - 1) / TY, NB); };

    // L1+L2+L3+pool fused: x0,c0 -> FA (x1,c1 full res) + HP (pooled half res)
    enc_full_kernel<<<dim3(W0 / FTW, H0 / FTH, NB), 128, 0, stream>>>(
        x0, c0, w1, b1, w2, b2, w3, b3, FAx, FAc, HPx, HPc, H0, W0);

    // L5: HP -> HA (w2,b2)
    navg5_kernel<2><<<gdim(W1, H1), blk, 0, stream>>>(HPx, HPc, w2, b2, HAx, HAc, H1, W1);
    // L6: HA -> HP (w3,b3)   [HP := x2_ds,c2_ds]
    navg5_kernel<2><<<gdim(W1, H1), blk, 0, stream>>>(HAx, HAc, w3, b3, HPx, HPc, H1, W1);
    // pool -> quarter
    pool_kernel<<<(int)((2 * n2 + 255) / 256), 256, 0, stream>>>(HPx, HPc, QPx, QPc, H2, W2);
    // L8: QP -> QA (w2,b2)   [QA := x3_ds,c3_ds]
    navg5_kernel<2><<<gdim(W2, H2), blk, 0, stream>>>(QPx, QPc, w2, b2, QAx, QAc, H2, W2);
    // pool -> eighth
    pool_kernel<<<(int)((2 * n3 + 255) / 256), 256, 0, stream>>>(QAx, QAc, EPx, EPc, H3, W3);
    // L10: EP -> EA (w2,b2)  [EA := x4_ds,c4_ds]
    navg5_kernel<2><<<gdim(W3, H3), blk, 0, stream>>>(EPx, EPc, w2, b2, EAx, EAc, H3, W3);
    // L12: cat(QA, up2(EA)) -> QP (w34,b34)
    navg3_kernel<false, true, false><<<gdim(W2, H2), blk, 0, stream>>>(
        QAx, QAc, EAx, EAc, w34, b34, nullptr, nullptr, QPx, QPc, H2, W2);
    // L14: cat(HP, up2(QP)) -> HA (w23,b23)
    navg3_kernel<false, true, false><<<gdim(W1, H1), blk, 0, stream>>>(
        HPx, HPc, QPx, QPc, w23, b23, nullptr, nullptr, HAx, HAc, H1, W1);
    // L16 + L17 fused: cat(up2(HA), FA) -> full res, then 1x1 w4, fp32 out
    navg3_kernel<true, false, true><<<gdim(W0, H0), blk, 0, stream>>>(
        HAx, HAc, FAx, FAc, w12, b12, w4, b4, out, out + n0, H0, W0);
}